// Round 1
// baseline (21662.598 us; speedup 1.0000x reference)
//
#include <hip/hip_runtime.h>
#include <hip/hip_bf16.h>

// Problem: B=64, T=512, D=H=1024 LSTM with variable lengths.
// Strategy: single persistent kernel (256 WGs = 256 CUs), weight-stationary
// bf16 fragments in VGPRs, fused [h|x] K=2048 MFMA per step, one hand-rolled
// device-scope grid barrier per step.

#define NB 64
#define NT 512
#define ND 1024
#define NWG 256

typedef __attribute__((ext_vector_type(8))) short bf16x8;
typedef __attribute__((ext_vector_type(4))) float f32x4;
typedef unsigned short u16;

__device__ __forceinline__ short f2bf(float f) {
  __hip_bfloat16 h = __float2bfloat16(f);  // RNE
  return __builtin_bit_cast(short, h);
}

// ---- ws layout ----
// [0,256)                   : barrier {count, gen}
// [256, 256+2*NB*ND*2)      : h ping-pong, bf16 [2][NB][ND]
// [262400, 262400+NT*NB*ND*2): x transposed+converted, bf16 [NT][NB][ND]
#define HB_OFF 256
#define XB_OFF (256 + 2 * NB * ND * 2)

__global__ void init_ws(unsigned* __restrict__ p) {
  const int n = (HB_OFF + 2 * NB * ND * 2) / 4;
  for (int i = blockIdx.x * blockDim.x + threadIdx.x; i < n;
       i += gridDim.x * blockDim.x)
    p[i] = 0u;
}

// x [B][T][D] f32  ->  xbf [T][B][D] bf16
__global__ void convert_x(const float* __restrict__ x, u16* __restrict__ xbf) {
  const int idx = blockIdx.x * blockDim.x + threadIdx.x;  // one per 4 floats
  const int d4 = idx & 255;           // D/4 = 256
  const int t  = (idx >> 8) & 511;    // T = 512
  const int b  = idx >> 17;
  float4 v = reinterpret_cast<const float4*>(x)[idx];
  ushort4 o;
  o.x = (u16)f2bf(v.x); o.y = (u16)f2bf(v.y);
  o.z = (u16)f2bf(v.z); o.w = (u16)f2bf(v.w);
  reinterpret_cast<ushort4*>(xbf)[((t * NB + b) << 8) + d4] = o;
}

__device__ __forceinline__ void grid_barrier(unsigned* bar, unsigned target) {
  __syncthreads();
  if (threadIdx.x == 0) {
    __threadfence();
    unsigned prev = __hip_atomic_fetch_add(&bar[0], 1u, __ATOMIC_ACQ_REL,
                                           __HIP_MEMORY_SCOPE_AGENT);
    if (prev == NWG - 1) {
      __hip_atomic_store(&bar[0], 0u, __ATOMIC_RELAXED,
                         __HIP_MEMORY_SCOPE_AGENT);
      __hip_atomic_store(&bar[1], target, __ATOMIC_RELEASE,
                         __HIP_MEMORY_SCOPE_AGENT);
    } else {
      while (__hip_atomic_load(&bar[1], __ATOMIC_ACQUIRE,
                               __HIP_MEMORY_SCOPE_AGENT) < target) {
        __builtin_amdgcn_s_sleep(2);
      }
    }
  }
  __syncthreads();
}

__global__ __launch_bounds__(256, 1) void lstm_main(
    const int* __restrict__ lengths,
    const float* __restrict__ Wi, const float* __restrict__ Ws,
    const float* __restrict__ bias,
    float* __restrict__ out,
    u16* __restrict__ hbuf, const u16* __restrict__ xbf,
    unsigned* __restrict__ bar) {
  __shared__ float lds_g[NB * 20];  // [64 batches][16 units + pad 4]
  const int tid  = threadIdx.x;
  const int cu   = blockIdx.x;
  const int lane = tid & 63;
  const int wid  = tid >> 6;
  const int j0   = cu << 2;  // this CU owns hidden j0..j0+3 (x 4 gates = 16 units)

  // ---- stationary weight fragments (B operand, col = unit = lane&15) ----
  // unit n: gate kg = n&3, hidden local jl = n>>2  (so LDS cols jl*4+k are a float4)
  const int n  = lane & 15;
  const int kg = n & 3;
  const int jl = n >> 2;
  const int kq = (lane >> 4) << 3;  // k offset within a 32-wide K block
  const float* wsrow = Ws + (size_t)(kg * ND + (j0 + jl)) * ND + kq;
  const float* wirow = Wi + (size_t)(kg * ND + (j0 + jl)) * ND + kq;
  bf16x8 w[64];
#pragma unroll
  for (int kb = 0; kb < 64; ++kb) {
    const float* src = (kb < 32) ? (wsrow + kb * 32) : (wirow + (kb - 32) * 32);
    float4 v0 = reinterpret_cast<const float4*>(src)[0];
    float4 v1 = reinterpret_cast<const float4*>(src)[1];
    bf16x8 wv;
    wv[0] = f2bf(v0.x); wv[1] = f2bf(v0.y); wv[2] = f2bf(v0.z); wv[3] = f2bf(v0.w);
    wv[4] = f2bf(v1.x); wv[5] = f2bf(v1.y); wv[6] = f2bf(v1.z); wv[7] = f2bf(v1.w);
    w[kb] = wv;
  }

  // ---- elementwise ownership: thread -> (batch eb, hidden-local ejl) ----
  const int eb  = tid >> 2;
  const int ejl = tid & 3;
  const int ej  = j0 + ejl;
  const int Lb  = lengths[eb];
  const float bi  = bias[0 * ND + ej];
  const float bff = bias[1 * ND + ej];
  const float bm  = bias[2 * ND + ej];
  const float bo  = bias[3 * ND + ej];
  float c = 0.f, hold = 0.f;

  const int am = (wid << 4) + (lane & 15);  // A row = batch (wave m-tile)

#pragma unroll 1
  for (int t = 0; t < NT; ++t) {
    const u16* ha = hbuf + (size_t)(t & 1) * (NB * ND) + am * ND + kq;
    const u16* xa = xbf + (size_t)t * (NB * ND) + am * ND + kq;
    f32x4 acc[4];
#pragma unroll
    for (int q = 0; q < 4; ++q) acc[q] = (f32x4){0.f, 0.f, 0.f, 0.f};
#pragma unroll
    for (int kb = 0; kb < 64; ++kb) {
      const u16* p = (kb < 32) ? (ha + kb * 32) : (xa + (kb - 32) * 32);
      bf16x8 a = *reinterpret_cast<const bf16x8*>(p);
      acc[kb & 3] =
          __builtin_amdgcn_mfma_f32_16x16x32_bf16(a, w[kb], acc[kb & 3], 0, 0, 0);
    }
    f32x4 cs = (acc[0] + acc[1]) + (acc[2] + acc[3]);
    {
      const int row0 = (wid << 4) + ((lane >> 4) << 2);
      const int col  = lane & 15;
#pragma unroll
      for (int r = 0; r < 4; ++r) lds_g[(row0 + r) * 20 + col] = cs[r];
    }
    __syncthreads();
    float4 g = *reinterpret_cast<const float4*>(&lds_g[eb * 20 + (ejl << 2)]);
    float gi = 1.f / (1.f + __expf(-(g.x + bi)));
    float gf = 1.f / (1.f + __expf(-(g.y + bff)));
    float gm = tanhf(g.z + bm);
    float go = 1.f / (1.f + __expf(-(g.w + bo)));
    float cn = gi * gm + gf * c;
    float hn = go * tanhf(cn);
    const bool valid = (t < Lb);
    c    = valid ? cn : c;
    hold = valid ? hn : hold;
    out[(size_t)(eb * NT + t) * ND + ej] = valid ? hn : 0.f;
    u16* hw = hbuf + (size_t)((t + 1) & 1) * (NB * ND);
    hw[eb * ND + ej] = (u16)f2bf(hold);
    grid_barrier(bar, t + 1);
  }
  // finals: hT then cT, each [1][B][H]
  out[(size_t)NB * NT * ND + (size_t)eb * ND + ej] = hold;
  out[(size_t)NB * NT * ND + (size_t)NB * ND + (size_t)eb * ND + ej] = c;
}

extern "C" void kernel_launch(void* const* d_in, const int* in_sizes, int n_in,
                              void* d_out, int out_size, void* d_ws,
                              size_t ws_size, hipStream_t stream) {
  const float* x       = (const float*)d_in[0];
  const int* lengths   = (const int*)d_in[1];
  const float* Wi      = (const float*)d_in[2];
  const float* Ws      = (const float*)d_in[3];
  const float* bias    = (const float*)d_in[4];
  float* out           = (float*)d_out;
  unsigned char* ws    = (unsigned char*)d_ws;
  unsigned* bar        = (unsigned*)ws;
  u16* hbuf            = (u16*)(ws + HB_OFF);
  u16* xbf             = (u16*)(ws + XB_OFF);

  hipLaunchKernelGGL(init_ws, dim3(64), dim3(256), 0, stream, bar);
  hipLaunchKernelGGL(convert_x, dim3((NB * NT * ND / 4) / 256), dim3(256), 0,
                     stream, x, xbf);
  hipLaunchKernelGGL(lstm_main, dim3(NWG), dim3(256), 0, stream, lengths, Wi,
                     Ws, bias, out, hbuf, xbf, bar);
}

// Round 4
// 5898.285 us; speedup vs baseline: 3.6727x; 3.6727x over previous
//
#include <hip/hip_runtime.h>
#include <hip/hip_bf16.h>

// R2 (2nd resubmit after infra timeouts): persistent LSTM, fine-grained
// coherence (sc0/sc1 write-through h, bypass h reads), RELAXED monotonic
// counter barrier (no wbl2/inv), x prefetch before the gate, 5-deep
// counted-vmcnt load pipeline.

#define NB 64
#define NT 512
#define ND 1024
#define NWG 256

typedef __attribute__((ext_vector_type(8))) short bf16x8;
typedef __attribute__((ext_vector_type(4))) float f32x4;
typedef unsigned short u16;

__device__ __forceinline__ short f2bf(float f) {
  __hip_bfloat16 h = __float2bfloat16(f);  // RNE
  return __builtin_bit_cast(short, h);
}

// ---- ws layout ----
#define HB_OFF 256
#define XB_OFF (256 + 2 * NB * ND * 2)

__global__ void init_ws(unsigned* __restrict__ p) {
  const int n = (HB_OFF + 2 * NB * ND * 2) / 4;
  for (int i = blockIdx.x * blockDim.x + threadIdx.x; i < n;
       i += gridDim.x * blockDim.x)
    p[i] = 0u;
}

// x [B][T][D] f32  ->  xbf [T][B][D] bf16
__global__ void convert_x(const float* __restrict__ x, u16* __restrict__ xbf) {
  const int idx = blockIdx.x * blockDim.x + threadIdx.x;  // one per 4 floats
  const int d4 = idx & 255;
  const int t  = (idx >> 8) & 511;
  const int b  = idx >> 17;
  float4 v = reinterpret_cast<const float4*>(x)[idx];
  ushort4 o;
  o.x = (u16)f2bf(v.x); o.y = (u16)f2bf(v.y);
  o.z = (u16)f2bf(v.z); o.w = (u16)f2bf(v.w);
  reinterpret_cast<ushort4*>(xbf)[((t * NB + b) << 8) + d4] = o;
}

// ---- fine-grained memory helpers ----
#define WAITV(N)                                             \
  do {                                                       \
    asm volatile("s_waitcnt vmcnt(" #N ")" ::: "memory");    \
    __builtin_amdgcn_sched_barrier(0);                       \
  } while (0)

__device__ __forceinline__ void gload4_c(bf16x8& d0, bf16x8& d1, bf16x8& d2,
                                         bf16x8& d3, const u16* p) {
  asm volatile(
      "global_load_dwordx4 %0, %4, off\n\t"
      "global_load_dwordx4 %1, %4, off offset:64\n\t"
      "global_load_dwordx4 %2, %4, off offset:128\n\t"
      "global_load_dwordx4 %3, %4, off offset:192"
      : "=&v"(d0), "=&v"(d1), "=&v"(d2), "=&v"(d3)
      : "v"(p));
}
__device__ __forceinline__ void gload4_b(bf16x8& d0, bf16x8& d1, bf16x8& d2,
                                         bf16x8& d3, const u16* p) {
  asm volatile(
      "global_load_dwordx4 %0, %4, off sc0 sc1\n\t"
      "global_load_dwordx4 %1, %4, off offset:64 sc0 sc1\n\t"
      "global_load_dwordx4 %2, %4, off offset:128 sc0 sc1\n\t"
      "global_load_dwordx4 %3, %4, off offset:192 sc0 sc1"
      : "=&v"(d0), "=&v"(d1), "=&v"(d2), "=&v"(d3)
      : "v"(p));
}
__device__ __forceinline__ void gstore_b16_wt(u16* p, unsigned v) {
  asm volatile("global_store_short %0, %1, off sc0 sc1" ::"v"(p), "v"(v)
               : "memory");
}

__device__ __forceinline__ float sigm(float z) {
  return 1.f / (1.f + __expf(-z));
}
__device__ __forceinline__ float tanh_f(float z) {
  return 1.f - 2.f / (1.f + __expf(2.f * z));
}

__global__ __launch_bounds__(256, 1) void lstm_main(
    const int* __restrict__ lengths, const float* __restrict__ Wi,
    const float* __restrict__ Ws, const float* __restrict__ bias,
    float* __restrict__ out, u16* __restrict__ hbuf,
    const u16* __restrict__ xbf, unsigned* __restrict__ bar) {
  __shared__ float lds_g[NB * 20];
  const int tid  = threadIdx.x;
  const int cu   = blockIdx.x;
  const int lane = tid & 63;
  const int wid  = tid >> 6;
  const int j0   = cu << 2;

  // ---- stationary weight fragments ----
  const int n  = lane & 15;
  const int kg = n & 3;
  const int jl = n >> 2;
  const int kq = (lane >> 4) << 3;
  const float* wsrow = Ws + (size_t)(kg * ND + (j0 + jl)) * ND + kq;
  const float* wirow = Wi + (size_t)(kg * ND + (j0 + jl)) * ND + kq;
  bf16x8 w[64];
#pragma unroll
  for (int kb = 0; kb < 64; ++kb) {
    const float* src = (kb < 32) ? (wsrow + kb * 32) : (wirow + (kb - 32) * 32);
    float4 v0 = reinterpret_cast<const float4*>(src)[0];
    float4 v1 = reinterpret_cast<const float4*>(src)[1];
    bf16x8 wv;
    wv[0] = f2bf(v0.x); wv[1] = f2bf(v0.y); wv[2] = f2bf(v0.z); wv[3] = f2bf(v0.w);
    wv[4] = f2bf(v1.x); wv[5] = f2bf(v1.y); wv[6] = f2bf(v1.z); wv[7] = f2bf(v1.w);
    w[kb] = wv;
  }

  const int eb  = tid >> 2;
  const int ejl = tid & 3;
  const int ej  = j0 + ejl;
  const int Lb  = lengths[eb];
  const float bi  = bias[0 * ND + ej];
  const float bff = bias[1 * ND + ej];
  const float bm  = bias[2 * ND + ej];
  const float bo  = bias[3 * ND + ej];
  float c = 0.f, hold = 0.f;

  const int am = (wid << 4) + (lane & 15);

  // consume order: X0..X3, H0..H3, X4..X7, H4..H7 (4 blocks each)
  constexpr int KIND[16] = {0, 0, 0, 0, 1, 1, 1, 1, 0, 0, 0, 0, 1, 1, 1, 1};
  constexpr int IDX[16]  = {0, 1, 2, 3, 0, 1, 2, 3, 4, 5, 6, 7, 4, 5, 6, 7};

  bf16x8 xd[8][4];
  bf16x8 hd[8][4];

#pragma unroll 1
  for (int t = 0; t < NT; ++t) {
    const u16* xb = xbf + (size_t)t * (NB * ND) + am * ND + kq;
    const u16* hb = hbuf + (size_t)(t & 1) * (NB * ND) + am * ND + kq;
    f32x4 acc[4];
#pragma unroll
    for (int q = 0; q < 4; ++q) acc[q] = (f32x4){0.f, 0.f, 0.f, 0.f};

    // pre-gate x prefetch (L2-cacheable, independent of h(t))
    gload4_c(xd[0][0], xd[0][1], xd[0][2], xd[0][3], xb);
    gload4_c(xd[1][0], xd[1][1], xd[1][2], xd[1][3], xb + 128);
    gload4_c(xd[2][0], xd[2][1], xd[2][2], xd[2][3], xb + 256);
    gload4_c(xd[3][0], xd[3][1], xd[3][2], xd[3][3], xb + 384);

    // gate: wait for all WGs to have produced h(t)
    if (tid == 0) {
      const unsigned tgt = (unsigned)NWG * (unsigned)t;
      while (__hip_atomic_load(&bar[0], __ATOMIC_RELAXED,
                               __HIP_MEMORY_SCOPE_AGENT) < tgt)
        __builtin_amdgcn_s_sleep(2);
    }
    __syncthreads();

    gload4_b(hd[0][0], hd[0][1], hd[0][2], hd[0][3], hb);

#pragma unroll
    for (int i = 0; i < 16; ++i) {
      if (i + 5 < 16) {
        const int mk = IDX[i + 5];
        if (KIND[i + 5] == 0) {
          if (mk == 4) gload4_c(xd[4][0], xd[4][1], xd[4][2], xd[4][3], xb + 512);
          if (mk == 5) gload4_c(xd[5][0], xd[5][1], xd[5][2], xd[5][3], xb + 640);
          if (mk == 6) gload4_c(xd[6][0], xd[6][1], xd[6][2], xd[6][3], xb + 768);
          if (mk == 7) gload4_c(xd[7][0], xd[7][1], xd[7][2], xd[7][3], xb + 896);
        } else {
          if (mk == 0) gload4_b(hd[0][0], hd[0][1], hd[0][2], hd[0][3], hb);
          if (mk == 1) gload4_b(hd[1][0], hd[1][1], hd[1][2], hd[1][3], hb + 128);
          if (mk == 2) gload4_b(hd[2][0], hd[2][1], hd[2][2], hd[2][3], hb + 256);
          if (mk == 3) gload4_b(hd[3][0], hd[3][1], hd[3][2], hd[3][3], hb + 384);
          if (mk == 4) gload4_b(hd[4][0], hd[4][1], hd[4][2], hd[4][3], hb + 512);
          if (mk == 5) gload4_b(hd[5][0], hd[5][1], hd[5][2], hd[5][3], hb + 640);
          if (mk == 6) gload4_b(hd[6][0], hd[6][1], hd[6][2], hd[6][3], hb + 768);
          if (mk == 7) gload4_b(hd[7][0], hd[7][1], hd[7][2], hd[7][3], hb + 896);
        }
      }
      if (i <= 10) { WAITV(20); }
      else if (i == 11) { WAITV(16); }
      else if (i == 12) { WAITV(12); }
      else if (i == 13) { WAITV(8); }
      else if (i == 14) { WAITV(4); }
      else { WAITV(0); }
      const int k = IDX[i];
      if (KIND[i] == 0) {
#pragma unroll
        for (int j = 0; j < 4; ++j)
          acc[j] = __builtin_amdgcn_mfma_f32_16x16x32_bf16(
              xd[k][j], w[32 + 4 * k + j], acc[j], 0, 0, 0);
      } else {
#pragma unroll
        for (int j = 0; j < 4; ++j)
          acc[j] = __builtin_amdgcn_mfma_f32_16x16x32_bf16(
              hd[k][j], w[4 * k + j], acc[j], 0, 0, 0);
      }
    }

    f32x4 cs = (acc[0] + acc[1]) + (acc[2] + acc[3]);
    {
      const int row0 = (wid << 4) + ((lane >> 4) << 2);
      const int col  = lane & 15;
#pragma unroll
      for (int r = 0; r < 4; ++r) lds_g[(row0 + r) * 20 + col] = cs[r];
    }
    __syncthreads();
    float4 g = *reinterpret_cast<const float4*>(&lds_g[eb * 20 + (ejl << 2)]);
    float gi = sigm(g.x + bi);
    float gf = sigm(g.y + bff);
    float gm = tanh_f(g.z + bm);
    float go = sigm(g.w + bo);
    float cn = gi * gm + gf * c;
    float hn = go * tanh_f(cn);
    const bool valid = (t < Lb);
    c    = valid ? cn : c;
    hold = valid ? hn : hold;
    out[(size_t)(eb * NT + t) * ND + ej] = valid ? hn : 0.f;
    u16* hw = hbuf + (size_t)((t + 1) & 1) * (NB * ND) + eb * ND + ej;
    gstore_b16_wt(hw, (unsigned)(u16)f2bf(hold));

    WAITV(0);          // all this wave's loads+stores complete (write-through)
    __syncthreads();   // all 4 waves done
    if (tid == 0)
      __hip_atomic_fetch_add(&bar[0], 1u, __ATOMIC_RELAXED,
                             __HIP_MEMORY_SCOPE_AGENT);
  }

  out[(size_t)NB * NT * ND + (size_t)eb * ND + ej] = hold;
  out[(size_t)NB * NT * ND + (size_t)NB * ND + (size_t)eb * ND + ej] = c;
}

extern "C" void kernel_launch(void* const* d_in, const int* in_sizes, int n_in,
                              void* d_out, int out_size, void* d_ws,
                              size_t ws_size, hipStream_t stream) {
  const float* x     = (const float*)d_in[0];
  const int* lengths = (const int*)d_in[1];
  const float* Wi    = (const float*)d_in[2];
  const float* Ws    = (const float*)d_in[3];
  const float* bias  = (const float*)d_in[4];
  float* out         = (float*)d_out;
  unsigned char* ws  = (unsigned char*)d_ws;
  unsigned* bar      = (unsigned*)ws;
  u16* hbuf          = (u16*)(ws + HB_OFF);
  u16* xbf           = (u16*)(ws + XB_OFF);

  hipLaunchKernelGGL(init_ws, dim3(64), dim3(256), 0, stream, bar);
  hipLaunchKernelGGL(convert_x, dim3((NB * NT * ND / 4) / 256), dim3(256), 0,
                     stream, x, xbf);
  hipLaunchKernelGGL(lstm_main, dim3(NWG), dim3(256), 0, stream, lengths, Wi,
                     Ws, bias, out, hbuf, xbf, bar);
}